// Round 2
// baseline (1049.363 us; speedup 1.0000x reference)
//
#include <hip/hip_runtime.h>
#include <math.h>

#define DD 16
#define LL 1024
#define BB 1024
#define NCHUNK (LL/4)            // 256 chunks of 4 steps
#define RSTRIDE 20               // floats per LDS row (64B data + 16B pad -> write spread)
#define ISTRIDE (16*RSTRIDE + 8) // 328 floats per item slot (items skewed by 8 banks)

// ---------------------------------------------------------------------------
// Kernel A: build chunk table (unchanged, verified).
// T[c*16+m] = K(4c,m>>3&1) @ K(4c+1,m>>2&1) @ K(4c+2,m>>1&1) @ K(4c+3,m&1)
// ---------------------------------------------------------------------------
__global__ void build_table(const float* __restrict__ km, float* __restrict__ T) {
    const int c = blockIdx.x >> 4;
    const int m = blockIdx.x & 15;
    const int t = threadIdx.x;
    const int i = t >> 4, k = t & 15;
    __shared__ float M[4][256];
    __shared__ float buf[256];
    const int xs0 = (m >> 3) & 1, xs1 = (m >> 2) & 1, xs2 = (m >> 1) & 1, xs3 = m & 1;
    M[0][t] = km[((4*c + 0)*2 + xs0)*256 + t];
    M[1][t] = km[((4*c + 1)*2 + xs1)*256 + t];
    M[2][t] = km[((4*c + 2)*2 + xs2)*256 + t];
    M[3][t] = km[((4*c + 3)*2 + xs3)*256 + t];
    __syncthreads();
    float acc = 0.f;
    #pragma unroll
    for (int j = 0; j < 16; ++j) acc += M[0][i*16+j] * M[1][j*16+k];
    buf[t] = acc;
    __syncthreads();
    acc = 0.f;
    #pragma unroll
    for (int j = 0; j < 16; ++j) acc += buf[i*16+j] * M[2][j*16+k];
    __syncthreads();
    buf[t] = acc;
    __syncthreads();
    acc = 0.f;
    #pragma unroll
    for (int j = 0; j < 16; ++j) acc += buf[i*16+j] * M[3][j*16+k];
    T[(size_t)blockIdx.x*256 + t] = acc;
}

// ---------------------------------------------------------------------------
// Kernel B: per-(batch, segment) partial products, LDS-staged + prefetch.
// Block = 256 threads = batch b, 16 segments x 16 threads. S=16, 16 chunk
// steps per segment. Thread j owns carry row j in registers.
// ---------------------------------------------------------------------------
__global__ void seg_prod4(const float* __restrict__ T, const int* __restrict__ x,
                          float* __restrict__ P) {
    __shared__ int4  xs4[NCHUNK];          // 4 KiB: x[b,:] packed as chunk nibbles
    __shared__ float mats[16 * ISTRIDE];   // 20.5 KiB: one 16x16 matrix per item
    const int tid  = threadIdx.x;
    const int item = tid >> 4;             // segment s (0..15)
    const int j    = tid & 15;             // carry row
    const int b    = blockIdx.x;

    xs4[tid] = reinterpret_cast<const int4*>(x + (size_t)b * LL)[tid];
    __syncthreads();

    const int base = item * 16;            // first chunk of this segment

    float c[16];
    #pragma unroll
    for (int q = 0; q < 16; ++q) c[q] = (q == j) ? 1.f : 0.f;

    // prologue: stage chunk `base`
    {
        const int4 xv = xs4[base];
        const int m = xv.x*8 + xv.y*4 + xv.z*2 + xv.w;
        const float4* gp = reinterpret_cast<const float4*>(
            T + ((size_t)base*16 + m)*256 + j*16);
        float4 r0 = gp[0], r1 = gp[1], r2 = gp[2], r3 = gp[3];
        float4* w = reinterpret_cast<float4*>(&mats[item*ISTRIDE + j*RSTRIDE]);
        w[0]=r0; w[1]=r1; w[2]=r2; w[3]=r3;
    }
    __syncthreads();

    #pragma unroll 1
    for (int cc = 0; cc < 16; ++cc) {
        // prefetch next chunk's row j into registers (addresses independent of carry)
        float4 r0, r1, r2, r3;
        const bool pf = (cc < 15);
        if (pf) {
            const int cidx = base + cc + 1;
            const int4 xv = xs4[cidx];
            const int m = xv.x*8 + xv.y*4 + xv.z*2 + xv.w;
            const float4* gp = reinterpret_cast<const float4*>(
                T + ((size_t)cidx*16 + m)*256 + j*16);
            r0 = gp[0]; r1 = gp[1]; r2 = gp[2]; r3 = gp[3];
        }
        // compute: c = c @ M  (M in LDS; 16-lane broadcast reads, bank-skewed)
        const float* M = &mats[item * ISTRIDE];
        float4 n0 = make_float4(0.f,0.f,0.f,0.f), n1 = n0, n2 = n0, n3 = n0;
        #pragma unroll
        for (int i = 0; i < 16; ++i) {
            const float a = c[i];
            const float4* mr = reinterpret_cast<const float4*>(M + i*RSTRIDE);
            const float4 q0 = mr[0], q1 = mr[1], q2 = mr[2], q3 = mr[3];
            n0.x += a*q0.x; n0.y += a*q0.y; n0.z += a*q0.z; n0.w += a*q0.w;
            n1.x += a*q1.x; n1.y += a*q1.y; n1.z += a*q1.z; n1.w += a*q1.w;
            n2.x += a*q2.x; n2.y += a*q2.y; n2.z += a*q2.z; n2.w += a*q2.w;
            n3.x += a*q3.x; n3.y += a*q3.y; n3.z += a*q3.z; n3.w += a*q3.w;
        }
        c[0]=n0.x; c[1]=n0.y; c[2]=n0.z; c[3]=n0.w;
        c[4]=n1.x; c[5]=n1.y; c[6]=n1.z; c[7]=n1.w;
        c[8]=n2.x; c[9]=n2.y; c[10]=n2.z; c[11]=n2.w;
        c[12]=n3.x; c[13]=n3.y; c[14]=n3.z; c[15]=n3.w;
        __syncthreads();                    // everyone done reading mats
        if (pf) {
            float* w = &mats[item*ISTRIDE + j*RSTRIDE];
            reinterpret_cast<float4*>(w)[0] = r0;
            reinterpret_cast<float4*>(w)[1] = r1;
            reinterpret_cast<float4*>(w)[2] = r2;
            reinterpret_cast<float4*>(w)[3] = r3;
        }
        __syncthreads();                    // next matrix visible
    }

    float4* Pp = reinterpret_cast<float4*>(P + ((size_t)b*16 + item)*256 + j*16);
    Pp[0] = make_float4(c[0],c[1],c[2],c[3]);
    Pp[1] = make_float4(c[4],c[5],c[6],c[7]);
    Pp[2] = make_float4(c[8],c[9],c[10],c[11]);
    Pp[3] = make_float4(c[12],c[13],c[14],c[15]);
}

// ---------------------------------------------------------------------------
// Kernel C: combine 16 partials per batch (chain), LDS-staged + prefetch.
// 64 threads/block = 4 batches, 16 threads each.
// ---------------------------------------------------------------------------
__global__ void combine2(const float* __restrict__ P, float* __restrict__ out) {
    __shared__ float mats[4 * ISTRIDE];
    const int tid = threadIdx.x;
    const int g = tid >> 4;
    const int j = tid & 15;
    const int b = blockIdx.x * 4 + g;

    float c[16];
    {
        const float4* p0 = reinterpret_cast<const float4*>(P + (size_t)(b*16)*256 + j*16);
        const float4 v0 = p0[0], v1 = p0[1], v2 = p0[2], v3 = p0[3];
        c[0]=v0.x; c[1]=v0.y; c[2]=v0.z; c[3]=v0.w;
        c[4]=v1.x; c[5]=v1.y; c[6]=v1.z; c[7]=v1.w;
        c[8]=v2.x; c[9]=v2.y; c[10]=v2.z; c[11]=v2.w;
        c[12]=v3.x; c[13]=v3.y; c[14]=v3.z; c[15]=v3.w;
    }
    {   // prologue: stage s=1
        const float4* gp = reinterpret_cast<const float4*>(P + (size_t)(b*16+1)*256 + j*16);
        const float4 r0=gp[0], r1=gp[1], r2=gp[2], r3=gp[3];
        float4* w = reinterpret_cast<float4*>(&mats[g*ISTRIDE + j*RSTRIDE]);
        w[0]=r0; w[1]=r1; w[2]=r2; w[3]=r3;
    }
    __syncthreads();

    #pragma unroll 1
    for (int s = 1; s < 16; ++s) {
        float4 r0, r1, r2, r3;
        const bool pf = (s < 15);
        if (pf) {
            const float4* gp = reinterpret_cast<const float4*>(P + (size_t)(b*16+s+1)*256 + j*16);
            r0 = gp[0]; r1 = gp[1]; r2 = gp[2]; r3 = gp[3];
        }
        const float* M = &mats[g * ISTRIDE];
        float4 n0 = make_float4(0.f,0.f,0.f,0.f), n1 = n0, n2 = n0, n3 = n0;
        #pragma unroll
        for (int i = 0; i < 16; ++i) {
            const float a = c[i];
            const float4* mr = reinterpret_cast<const float4*>(M + i*RSTRIDE);
            const float4 q0 = mr[0], q1 = mr[1], q2 = mr[2], q3 = mr[3];
            n0.x += a*q0.x; n0.y += a*q0.y; n0.z += a*q0.z; n0.w += a*q0.w;
            n1.x += a*q1.x; n1.y += a*q1.y; n1.z += a*q1.z; n1.w += a*q1.w;
            n2.x += a*q2.x; n2.y += a*q2.y; n2.z += a*q2.z; n2.w += a*q2.w;
            n3.x += a*q3.x; n3.y += a*q3.y; n3.z += a*q3.z; n3.w += a*q3.w;
        }
        c[0]=n0.x; c[1]=n0.y; c[2]=n0.z; c[3]=n0.w;
        c[4]=n1.x; c[5]=n1.y; c[6]=n1.z; c[7]=n1.w;
        c[8]=n2.x; c[9]=n2.y; c[10]=n2.z; c[11]=n2.w;
        c[12]=n3.x; c[13]=n3.y; c[14]=n3.z; c[15]=n3.w;
        __syncthreads();
        if (pf) {
            float4* w = reinterpret_cast<float4*>(&mats[g*ISTRIDE + j*RSTRIDE]);
            w[0]=r0; w[1]=r1; w[2]=r2; w[3]=r3;
        }
        __syncthreads();
    }

    float diag = 0.f;
    #pragma unroll
    for (int k = 0; k < 16; ++k) diag = (k == j) ? c[k] : diag;
    #pragma unroll
    for (int off = 8; off >= 1; off >>= 1) diag += __shfl_xor(diag, off, 16);
    if (j == 0) out[b] = logf(diag);
}

// ---------------------------------------------------------------------------
// Fallback kernels (small-ws path) — verified in R1.
// ---------------------------------------------------------------------------
template<int CHUNK>
__global__ void seg_prod(const float* __restrict__ T, const int* __restrict__ x,
                         float* __restrict__ P, const int S, const int lgS) {
    const int tid  = blockIdx.x * blockDim.x + threadIdx.x;
    const int j    = tid & 15;
    const int item = tid >> 4;
    if (item >= BB * S) return;
    const int s = item & (S - 1);
    const int b = item >> lgS;
    float c[16];
    #pragma unroll
    for (int q = 0; q < 16; ++q) c[q] = (q == j) ? 1.f : 0.f;
    const int nsteps = (CHUNK == 4 ? NCHUNK : LL) / S;
    const int base   = s * nsteps;
    for (int cc = 0; cc < nsteps; ++cc) {
        const float4* __restrict__ Mrow;
        if (CHUNK == 4) {
            const int cidx = base + cc;
            const int4 xv = *reinterpret_cast<const int4*>(x + (size_t)b*LL + 4*cidx);
            const int m = xv.x*8 + xv.y*4 + xv.z*2 + xv.w;
            Mrow = reinterpret_cast<const float4*>(T + ((size_t)cidx*16 + m)*256);
        } else {
            const int l = base + cc;
            const int xv = x[(size_t)b*LL + l];
            Mrow = reinterpret_cast<const float4*>(T + ((size_t)l*2 + xv)*256);
        }
        float4 n0 = make_float4(0.f,0.f,0.f,0.f), n1 = n0, n2 = n0, n3 = n0;
        #pragma unroll
        for (int i = 0; i < 16; ++i) {
            const float a = c[i];
            const float4 r0 = Mrow[i*4+0], r1 = Mrow[i*4+1], r2 = Mrow[i*4+2], r3 = Mrow[i*4+3];
            n0.x += a*r0.x; n0.y += a*r0.y; n0.z += a*r0.z; n0.w += a*r0.w;
            n1.x += a*r1.x; n1.y += a*r1.y; n1.z += a*r1.z; n1.w += a*r1.w;
            n2.x += a*r2.x; n2.y += a*r2.y; n2.z += a*r2.z; n2.w += a*r2.w;
            n3.x += a*r3.x; n3.y += a*r3.y; n3.z += a*r3.z; n3.w += a*r3.w;
        }
        c[0]=n0.x; c[1]=n0.y; c[2]=n0.z; c[3]=n0.w;
        c[4]=n1.x; c[5]=n1.y; c[6]=n1.z; c[7]=n1.w;
        c[8]=n2.x; c[9]=n2.y; c[10]=n2.z; c[11]=n2.w;
        c[12]=n3.x; c[13]=n3.y; c[14]=n3.z; c[15]=n3.w;
    }
    float4* Pp = reinterpret_cast<float4*>(P + (size_t)item*256 + j*16);
    Pp[0] = make_float4(c[0],c[1],c[2],c[3]);
    Pp[1] = make_float4(c[4],c[5],c[6],c[7]);
    Pp[2] = make_float4(c[8],c[9],c[10],c[11]);
    Pp[3] = make_float4(c[12],c[13],c[14],c[15]);
}

__global__ void combine_gen(const float* __restrict__ P, float* __restrict__ out,
                            const int S) {
    const int g = threadIdx.x >> 4;
    const int j = threadIdx.x & 15;
    const int b = blockIdx.x * 4 + g;
    float c[16];
    {
        const float4* p0 = reinterpret_cast<const float4*>(P + (size_t)(b*S)*256 + j*16);
        const float4 v0 = p0[0], v1 = p0[1], v2 = p0[2], v3 = p0[3];
        c[0]=v0.x; c[1]=v0.y; c[2]=v0.z; c[3]=v0.w;
        c[4]=v1.x; c[5]=v1.y; c[6]=v1.z; c[7]=v1.w;
        c[8]=v2.x; c[9]=v2.y; c[10]=v2.z; c[11]=v2.w;
        c[12]=v3.x; c[13]=v3.y; c[14]=v3.z; c[15]=v3.w;
    }
    for (int s = 1; s < S; ++s) {
        const float4* Mrow = reinterpret_cast<const float4*>(P + (size_t)(b*S + s)*256);
        float4 n0 = make_float4(0.f,0.f,0.f,0.f), n1 = n0, n2 = n0, n3 = n0;
        #pragma unroll
        for (int i = 0; i < 16; ++i) {
            const float a = c[i];
            const float4 r0 = Mrow[i*4+0], r1 = Mrow[i*4+1], r2 = Mrow[i*4+2], r3 = Mrow[i*4+3];
            n0.x += a*r0.x; n0.y += a*r0.y; n0.z += a*r0.z; n0.w += a*r0.w;
            n1.x += a*r1.x; n1.y += a*r1.y; n1.z += a*r1.z; n1.w += a*r1.w;
            n2.x += a*r2.x; n2.y += a*r2.y; n2.z += a*r2.z; n2.w += a*r2.w;
            n3.x += a*r3.x; n3.y += a*r3.y; n3.z += a*r3.z; n3.w += a*r3.w;
        }
        c[0]=n0.x; c[1]=n0.y; c[2]=n0.z; c[3]=n0.w;
        c[4]=n1.x; c[5]=n1.y; c[6]=n1.z; c[7]=n1.w;
        c[8]=n2.x; c[9]=n2.y; c[10]=n2.z; c[11]=n2.w;
        c[12]=n3.x; c[13]=n3.y; c[14]=n3.z; c[15]=n3.w;
    }
    float diag = 0.f;
    #pragma unroll
    for (int k = 0; k < 16; ++k) diag = (k == j) ? c[k] : diag;
    #pragma unroll
    for (int off = 8; off >= 1; off >>= 1) diag += __shfl_xor(diag, off, 16);
    if (j == 0) out[b] = logf(diag);
}

// ---------------------------------------------------------------------------
extern "C" void kernel_launch(void* const* d_in, const int* in_sizes, int n_in,
                              void* d_out, int out_size, void* d_ws, size_t ws_size,
                              hipStream_t stream) {
    const int*   x  = (const int*)d_in[0];    // (B, L) int32
    const float* km = (const float*)d_in[1];  // (L, PHYS, D, D) fp32
    float* out = (float*)d_out;               // (B,) fp32

    const size_t tbytes = (size_t)NCHUNK * 16 * 256 * sizeof(float);   // 4 MiB
    const size_t pbytes = (size_t)BB * 16 * 256 * sizeof(float);       // 16 MiB

    if (ws_size >= tbytes + pbytes) {
        float* Tbl = (float*)d_ws;
        float* P   = (float*)((char*)d_ws + tbytes);
        build_table<<<NCHUNK*16, 256, 0, stream>>>(km, Tbl);
        seg_prod4<<<BB, 256, 0, stream>>>(Tbl, x, P);
        combine2<<<BB/4, 64, 0, stream>>>(P, out);
    } else {
        int S = 16;
        while (S > 1 && (size_t)BB * S * 256 * sizeof(float) > ws_size) S >>= 1;
        int lgS = 0; for (int t = S; t > 1; t >>= 1) ++lgS;
        float* P = (float*)d_ws;
        const int items = BB * S;
        const int blocks = (items*16 + 255) / 256;
        seg_prod<1><<<blocks, 256, 0, stream>>>(km, x, P, S, lgS);
        combine_gen<<<BB/4, 64, 0, stream>>>(P, out, S);
    }
}

// Round 3
// 248.621 us; speedup vs baseline: 4.2207x; 4.2207x over previous
//
#include <hip/hip_runtime.h>
#include <math.h>

#define DD 16
#define LL 1024
#define BB 1024
#define NCHUNK4 (LL/4)     // 256 chunks of 4 steps
#define NCHUNK8 (LL/8)     // 128 chunks of 8 steps
#define SSEG 32            // segments per batch (main path)

#define FMA4(acc, s, v) { (acc).x += (s)*(v).x; (acc).y += (s)*(v).y; \
                          (acc).z += (s)*(v).z; (acc).w += (s)*(v).w; }

// ---------------------------------------------------------------------------
// Kernel A1: 4-step chunk table (verified in R1/R2).
// T4[(c*16+m)*256 + i*16+k];  m bit3 <-> step 4c+0 (first factor).
// ---------------------------------------------------------------------------
__global__ __launch_bounds__(256) void build_table(const float* __restrict__ km,
                                                   float* __restrict__ T) {
    const int c = blockIdx.x >> 4;
    const int m = blockIdx.x & 15;
    const int t = threadIdx.x;
    const int i = t >> 4, k = t & 15;
    __shared__ float M[4][256];
    __shared__ float buf[256];
    const int xs0 = (m >> 3) & 1, xs1 = (m >> 2) & 1, xs2 = (m >> 1) & 1, xs3 = m & 1;
    M[0][t] = km[((4*c + 0)*2 + xs0)*256 + t];
    M[1][t] = km[((4*c + 1)*2 + xs1)*256 + t];
    M[2][t] = km[((4*c + 2)*2 + xs2)*256 + t];
    M[3][t] = km[((4*c + 3)*2 + xs3)*256 + t];
    __syncthreads();
    float acc = 0.f;
    #pragma unroll
    for (int j = 0; j < 16; ++j) acc += M[0][i*16+j] * M[1][j*16+k];
    buf[t] = acc;
    __syncthreads();
    acc = 0.f;
    #pragma unroll
    for (int j = 0; j < 16; ++j) acc += buf[i*16+j] * M[2][j*16+k];
    __syncthreads();
    buf[t] = acc;
    __syncthreads();
    acc = 0.f;
    #pragma unroll
    for (int j = 0; j < 16; ++j) acc += buf[i*16+j] * M[3][j*16+k];
    T[(size_t)blockIdx.x*256 + t] = acc;
}

// ---------------------------------------------------------------------------
// Kernel A2: 8-step chunk table from T4.
// T8[(c8*256+m8)*256] = T4[2c8][m8>>4] @ T4[2c8+1][m8&15]
// block = (c8, m8): grid 128*256.  m8 bit7 <-> step 8*c8+0.
// ---------------------------------------------------------------------------
__global__ __launch_bounds__(256) void build_table8(const float* __restrict__ T4,
                                                    float* __restrict__ T8) {
    const int c8 = blockIdx.x >> 8;
    const int m8 = blockIdx.x & 255;
    const int t = threadIdx.x;
    __shared__ float As[256], Bs[256];
    As[t] = T4[((size_t)(2*c8)*16 + (m8 >> 4))*256 + t];
    Bs[t] = T4[((size_t)(2*c8+1)*16 + (m8 & 15))*256 + t];
    __syncthreads();
    const int i = t >> 4, k = t & 15;
    float acc = 0.f;
    #pragma unroll
    for (int j = 0; j < 16; ++j) acc += As[i*16+j] * Bs[j*16+k];
    T8[(size_t)blockIdx.x*256 + t] = acc;
}

// ---------------------------------------------------------------------------
// Kernel B: segment products. item = b*32 + s; 8 threads/item; thread u owns
// carry rows 2u, 2u+1. 4 chunk8-steps per item. All m-indices precomputed.
// No LDS, no barriers; all arrays statically indexed (spill-safe).
// ---------------------------------------------------------------------------
#define SP_ROW(ii, a0s, a1s) { \
    const float4 q0 = Mp[(ii)*4+0], q1 = Mp[(ii)*4+1]; \
    const float4 q2 = Mp[(ii)*4+2], q3 = Mp[(ii)*4+3]; \
    FMA4(o0[0], (a0s), q0); FMA4(o0[1], (a0s), q1); \
    FMA4(o0[2], (a0s), q2); FMA4(o0[3], (a0s), q3); \
    FMA4(o1[0], (a1s), q0); FMA4(o1[1], (a1s), q1); \
    FMA4(o1[2], (a1s), q2); FMA4(o1[3], (a1s), q3); }

__global__ __launch_bounds__(256, 4) void seg_prod8(const float* __restrict__ T8,
                                                    const int* __restrict__ x,
                                                    float* __restrict__ P) {
    const int tid  = blockIdx.x * 256 + threadIdx.x;
    const int u    = tid & 7;          // rows 2u, 2u+1
    const int item = tid >> 3;         // b*SSEG + s
    const int s    = item & (SSEG-1);
    const int b    = item >> 5;

    // precompute the 4 combo indices (8 x-bits each)
    const int4* xp = reinterpret_cast<const int4*>(x + (size_t)b*LL + s*32);
    int mm[4];
    #pragma unroll
    for (int t = 0; t < 4; ++t) {
        const int4 w0 = xp[2*t], w1 = xp[2*t+1];
        mm[t] = (w0.x<<7)|(w0.y<<6)|(w0.z<<5)|(w0.w<<4)|(w1.x<<3)|(w1.y<<2)|(w1.z<<1)|w1.w;
    }

    const int r0 = 2*u, r1 = 2*u + 1;
    float4 c0[4], c1[4];
    #pragma unroll
    for (int q = 0; q < 4; ++q) {
        c0[q] = make_float4((float)(r0==4*q+0), (float)(r0==4*q+1),
                            (float)(r0==4*q+2), (float)(r0==4*q+3));
        c1[q] = make_float4((float)(r1==4*q+0), (float)(r1==4*q+1),
                            (float)(r1==4*q+2), (float)(r1==4*q+3));
    }

    #pragma unroll
    for (int t = 0; t < 4; ++t) {
        const float4* __restrict__ Mp = reinterpret_cast<const float4*>(T8)
                                      + ((size_t)(s*4 + t)*256 + mm[t])*64;
        float4 o0[4], o1[4];
        #pragma unroll
        for (int q = 0; q < 4; ++q) {
            o0[q] = make_float4(0.f,0.f,0.f,0.f);
            o1[q] = o0[q];
        }
        #pragma unroll
        for (int i4 = 0; i4 < 4; ++i4) {
            const float4 a0 = c0[i4], a1 = c1[i4];
            SP_ROW(4*i4+0, a0.x, a1.x);
            SP_ROW(4*i4+1, a0.y, a1.y);
            SP_ROW(4*i4+2, a0.z, a1.z);
            SP_ROW(4*i4+3, a0.w, a1.w);
        }
        #pragma unroll
        for (int q = 0; q < 4; ++q) { c0[q] = o0[q]; c1[q] = o1[q]; }
    }

    float4* Pp = reinterpret_cast<float4*>(P) + (size_t)item*64;
    #pragma unroll
    for (int q = 0; q < 4; ++q) {
        Pp[r0*4 + q] = c0[q];
        Pp[r1*4 + q] = c1[q];
    }
}

// ---------------------------------------------------------------------------
// Kernel C: per-batch 5-level tree combine of 32 partials + trace + log.
// Block = 1 batch, 256 threads. LDS: 48 matrix slots (stride 260 floats).
// Level l: nprod=16>>l products, 16 threads each (thread = output row j).
// ---------------------------------------------------------------------------
#define SLOT 260

#define CROW(ii, as) { \
    const float4 b0 = *reinterpret_cast<const float4*>(Bm + (ii)*16 + 0); \
    const float4 b1 = *reinterpret_cast<const float4*>(Bm + (ii)*16 + 4); \
    const float4 b2 = *reinterpret_cast<const float4*>(Bm + (ii)*16 + 8); \
    const float4 b3 = *reinterpret_cast<const float4*>(Bm + (ii)*16 + 12); \
    FMA4(o0, (as), b0); FMA4(o1, (as), b1); FMA4(o2, (as), b2); FMA4(o3, (as), b3); }

__global__ __launch_bounds__(256, 2) void combine32(const float* __restrict__ P,
                                                    float* __restrict__ out) {
    __shared__ float mats[48 * SLOT];
    const int t = threadIdx.x;
    const int b = blockIdx.x;

    // stage this batch's 32 partials (32 KiB), coalesced
    const float4* Pb = reinterpret_cast<const float4*>(P) + (size_t)b * 2048;
    #pragma unroll
    for (int k = 0; k < 8; ++k) {
        const int g = k*256 + t;             // 0..2047 float4s
        const float4 v = Pb[g];
        const int slot = g >> 6, w = g & 63;
        *reinterpret_cast<float4*>(&mats[slot*SLOT + w*4]) = v;
    }
    __syncthreads();

    const int p = t >> 4, j = t & 15;
    for (int l = 0; l < 5; ++l) {
        const int nprod = 16 >> l;
        const int src = (l & 1) ? 32 : 0;
        const int dst = src ^ 32;
        if (p < nprod) {
            const float* A  = &mats[(src + 2*p)*SLOT + j*16];
            const float* Bm = &mats[(src + 2*p + 1)*SLOT];
            const float4 a0 = *reinterpret_cast<const float4*>(A + 0);
            const float4 a1 = *reinterpret_cast<const float4*>(A + 4);
            const float4 a2 = *reinterpret_cast<const float4*>(A + 8);
            const float4 a3 = *reinterpret_cast<const float4*>(A + 12);
            float4 o0 = make_float4(0.f,0.f,0.f,0.f), o1 = o0, o2 = o0, o3 = o0;
            CROW(0,  a0.x); CROW(1,  a0.y); CROW(2,  a0.z); CROW(3,  a0.w);
            CROW(4,  a1.x); CROW(5,  a1.y); CROW(6,  a1.z); CROW(7,  a1.w);
            CROW(8,  a2.x); CROW(9,  a2.y); CROW(10, a2.z); CROW(11, a2.w);
            CROW(12, a3.x); CROW(13, a3.y); CROW(14, a3.z); CROW(15, a3.w);
            float* O = &mats[(dst + p)*SLOT + j*16];
            *reinterpret_cast<float4*>(O + 0)  = o0;
            *reinterpret_cast<float4*>(O + 4)  = o1;
            *reinterpret_cast<float4*>(O + 8)  = o2;
            *reinterpret_cast<float4*>(O + 12) = o3;
        }
        __syncthreads();
    }

    if (t < 16) {
        float d = mats[32*SLOT + t*16 + t];
        #pragma unroll
        for (int off = 8; off >= 1; off >>= 1) d += __shfl_xor(d, off, 16);
        if (t == 0) out[b] = logf(d);
    }
}

// ---------------------------------------------------------------------------
// Fallback kernels (verified R1 path).
// ---------------------------------------------------------------------------
template<int CHUNK>
__global__ void seg_prod(const float* __restrict__ T, const int* __restrict__ x,
                         float* __restrict__ P, const int S, const int lgS) {
    const int tid  = blockIdx.x * blockDim.x + threadIdx.x;
    const int j    = tid & 15;
    const int item = tid >> 4;
    if (item >= BB * S) return;
    const int s = item & (S - 1);
    const int b = item >> lgS;
    float c[16];
    #pragma unroll
    for (int q = 0; q < 16; ++q) c[q] = (q == j) ? 1.f : 0.f;
    const int nsteps = (CHUNK == 4 ? NCHUNK4 : LL) / S;
    const int base   = s * nsteps;
    for (int cc = 0; cc < nsteps; ++cc) {
        const float4* __restrict__ Mrow;
        if (CHUNK == 4) {
            const int cidx = base + cc;
            const int4 xv = *reinterpret_cast<const int4*>(x + (size_t)b*LL + 4*cidx);
            const int m = xv.x*8 + xv.y*4 + xv.z*2 + xv.w;
            Mrow = reinterpret_cast<const float4*>(T + ((size_t)cidx*16 + m)*256);
        } else {
            const int l = base + cc;
            const int xv = x[(size_t)b*LL + l];
            Mrow = reinterpret_cast<const float4*>(T + ((size_t)l*2 + xv)*256);
        }
        float4 n0 = make_float4(0.f,0.f,0.f,0.f), n1 = n0, n2 = n0, n3 = n0;
        #pragma unroll
        for (int i = 0; i < 16; ++i) {
            const float a = c[i];
            const float4 r0 = Mrow[i*4+0], r1 = Mrow[i*4+1], r2 = Mrow[i*4+2], r3 = Mrow[i*4+3];
            FMA4(n0, a, r0); FMA4(n1, a, r1); FMA4(n2, a, r2); FMA4(n3, a, r3);
        }
        c[0]=n0.x; c[1]=n0.y; c[2]=n0.z; c[3]=n0.w;
        c[4]=n1.x; c[5]=n1.y; c[6]=n1.z; c[7]=n1.w;
        c[8]=n2.x; c[9]=n2.y; c[10]=n2.z; c[11]=n2.w;
        c[12]=n3.x; c[13]=n3.y; c[14]=n3.z; c[15]=n3.w;
    }
    float4* Pp = reinterpret_cast<float4*>(P + (size_t)item*256 + j*16);
    Pp[0] = make_float4(c[0],c[1],c[2],c[3]);
    Pp[1] = make_float4(c[4],c[5],c[6],c[7]);
    Pp[2] = make_float4(c[8],c[9],c[10],c[11]);
    Pp[3] = make_float4(c[12],c[13],c[14],c[15]);
}

__global__ void combine_gen(const float* __restrict__ P, float* __restrict__ out,
                            const int S) {
    const int g = threadIdx.x >> 4;
    const int j = threadIdx.x & 15;
    const int b = blockIdx.x * 4 + g;
    float c[16];
    {
        const float4* p0 = reinterpret_cast<const float4*>(P + (size_t)(b*S)*256 + j*16);
        const float4 v0 = p0[0], v1 = p0[1], v2 = p0[2], v3 = p0[3];
        c[0]=v0.x; c[1]=v0.y; c[2]=v0.z; c[3]=v0.w;
        c[4]=v1.x; c[5]=v1.y; c[6]=v1.z; c[7]=v1.w;
        c[8]=v2.x; c[9]=v2.y; c[10]=v2.z; c[11]=v2.w;
        c[12]=v3.x; c[13]=v3.y; c[14]=v3.z; c[15]=v3.w;
    }
    for (int s = 1; s < S; ++s) {
        const float4* Mrow = reinterpret_cast<const float4*>(P + (size_t)(b*S + s)*256);
        float4 n0 = make_float4(0.f,0.f,0.f,0.f), n1 = n0, n2 = n0, n3 = n0;
        #pragma unroll
        for (int i = 0; i < 16; ++i) {
            const float a = c[i];
            const float4 r0 = Mrow[i*4+0], r1 = Mrow[i*4+1], r2 = Mrow[i*4+2], r3 = Mrow[i*4+3];
            FMA4(n0, a, r0); FMA4(n1, a, r1); FMA4(n2, a, r2); FMA4(n3, a, r3);
        }
        c[0]=n0.x; c[1]=n0.y; c[2]=n0.z; c[3]=n0.w;
        c[4]=n1.x; c[5]=n1.y; c[6]=n1.z; c[7]=n1.w;
        c[8]=n2.x; c[9]=n2.y; c[10]=n2.z; c[11]=n2.w;
        c[12]=n3.x; c[13]=n3.y; c[14]=n3.z; c[15]=n3.w;
    }
    float diag = 0.f;
    #pragma unroll
    for (int k = 0; k < 16; ++k) diag = (k == j) ? c[k] : diag;
    #pragma unroll
    for (int off = 8; off >= 1; off >>= 1) diag += __shfl_xor(diag, off, 16);
    if (j == 0) out[b] = logf(diag);
}

// ---------------------------------------------------------------------------
extern "C" void kernel_launch(void* const* d_in, const int* in_sizes, int n_in,
                              void* d_out, int out_size, void* d_ws, size_t ws_size,
                              hipStream_t stream) {
    const int*   x  = (const int*)d_in[0];    // (B, L) int32
    const float* km = (const float*)d_in[1];  // (L, PHYS, D, D) fp32
    float* out = (float*)d_out;               // (B,) fp32

    const size_t t4b = (size_t)NCHUNK4 * 16 * 256 * sizeof(float);    // 4 MiB
    const size_t t8b = (size_t)NCHUNK8 * 256 * 256 * sizeof(float);   // 32 MiB
    const size_t p32 = (size_t)BB * SSEG * 256 * sizeof(float);       // 32 MiB
    const size_t p16 = (size_t)BB * 16 * 256 * sizeof(float);         // 16 MiB

    if (ws_size >= t4b + t8b + p32) {
        // main path: CHUNK=8 table, S=32 segments, tree combine
        float* T4 = (float*)d_ws;
        float* T8 = (float*)((char*)d_ws + t4b);
        float* P  = (float*)((char*)d_ws + t4b + t8b);
        build_table<<<NCHUNK4*16, 256, 0, stream>>>(km, T4);
        build_table8<<<NCHUNK8*256, 256, 0, stream>>>(T4, T8);
        seg_prod8<<<BB*SSEG*8/256, 256, 0, stream>>>(T8, x, P);
        combine32<<<BB, 256, 0, stream>>>(P, out);
    } else if (ws_size >= t4b + p16) {
        // R1 verified path
        float* T4 = (float*)d_ws;
        float* P  = (float*)((char*)d_ws + t4b);
        build_table<<<NCHUNK4*16, 256, 0, stream>>>(km, T4);
        seg_prod<4><<<BB*16*16/256, 256, 0, stream>>>(T4, x, P, 16, 4);
        combine_gen<<<BB/4, 64, 0, stream>>>(P, out, 16);
    } else {
        int S = 16;
        while (S > 1 && (size_t)BB * S * 256 * sizeof(float) > ws_size) S >>= 1;
        int lgS = 0; for (int t = S; t > 1; t >>= 1) ++lgS;
        float* P = (float*)d_ws;
        const int blocks = (BB*S*16 + 255) / 256;
        seg_prod<1><<<blocks, 256, 0, stream>>>(km, x, P, S, lgS);
        combine_gen<<<BB/4, 64, 0, stream>>>(P, out, S);
    }
}

// Round 5
// 40.737 us; speedup vs baseline: 25.7592x; 6.1030x over previous
//
#include <hip/hip_runtime.h>
#include <math.h>

#define LL 1024
#define BB 1024
#define NCHUNK4 256
#define SEGS 8
#define STEPS 32           // chunk4 steps per segment
#define SLOT 260

typedef float f32x4 __attribute__((ext_vector_type(4)));
typedef short s16x8 __attribute__((ext_vector_type(8)));

#define FMA4(acc, s, v) { (acc).x += (s)*(v).x; (acc).y += (s)*(v).y; \
                          (acc).z += (s)*(v).z; (acc).w += (s)*(v).w; }

__device__ inline unsigned f2bf(float f) {   // RNE f32->bf16 bits
    unsigned u = __float_as_uint(f);
    return (u + 0x7FFFu + ((u >> 16) & 1u)) >> 16;
}

// ---------------------------------------------------------------------------
// Kernel A: 4-step chunk table in fp32 (verified R1-R3).
// T4[(c*16+m)*256 + i*16+k]; m bit3 <-> step 4c+0 (first factor).
// ---------------------------------------------------------------------------
__global__ __launch_bounds__(256) void build_table(const float* __restrict__ km,
                                                   float* __restrict__ T) {
    const int c = blockIdx.x >> 4;
    const int m = blockIdx.x & 15;
    const int t = threadIdx.x;
    const int i = t >> 4, k = t & 15;
    __shared__ float M[4][256];
    __shared__ float buf[256];
    const int xs0 = (m >> 3) & 1, xs1 = (m >> 2) & 1, xs2 = (m >> 1) & 1, xs3 = m & 1;
    M[0][t] = km[((4*c + 0)*2 + xs0)*256 + t];
    M[1][t] = km[((4*c + 1)*2 + xs1)*256 + t];
    M[2][t] = km[((4*c + 2)*2 + xs2)*256 + t];
    M[3][t] = km[((4*c + 3)*2 + xs3)*256 + t];
    __syncthreads();
    float acc = 0.f;
    #pragma unroll
    for (int j = 0; j < 16; ++j) acc += M[0][i*16+j] * M[1][j*16+k];
    buf[t] = acc;
    __syncthreads();
    acc = 0.f;
    #pragma unroll
    for (int j = 0; j < 16; ++j) acc += buf[i*16+j] * M[2][j*16+k];
    __syncthreads();
    buf[t] = acc;
    __syncthreads();
    acc = 0.f;
    #pragma unroll
    for (int j = 0; j < 16; ++j) acc += buf[i*16+j] * M[3][j*16+k];
    T[(size_t)blockIdx.x*256 + t] = acc;
}

// ---------------------------------------------------------------------------
// Kernel A2: repack T4 -> bf16 A-fragments of M^T for mfma_f32_16x16x32_bf16.
// Own slot convention: lane (g=l>>4, c=l&15), elems j=0..3 hold
// A[r=c][k-slot 4g+j] = M[4g+j][c]; elems 4..7 duplicate (second K-half,
// paired with the carry's lo part). Relabeling-invariance of the k
// contraction makes this correct for any HW k-slot map shared by A and B.
// ---------------------------------------------------------------------------
__global__ __launch_bounds__(256) void repackA(const float* __restrict__ T4,
                                               uint4* __restrict__ TA) {
    const int lane = threadIdx.x & 63;
    const int mat  = blockIdx.x*4 + (threadIdx.x >> 6);
    const int g = lane >> 4, c = lane & 15;
    const float* M = T4 + (size_t)mat*256;
    const unsigned a0 = f2bf(M[(4*g+0)*16 + c]);
    const unsigned a1 = f2bf(M[(4*g+1)*16 + c]);
    const unsigned a2 = f2bf(M[(4*g+2)*16 + c]);
    const unsigned a3 = f2bf(M[(4*g+3)*16 + c]);
    const unsigned w01 = a0 | (a1 << 16);
    const unsigned w23 = a2 | (a3 << 16);
    TA[(size_t)mat*64 + lane] = make_uint4(w01, w23, w01, w23);
}

// ---------------------------------------------------------------------------
// Kernel B: one wave per (batch,segment). Transposed chain R <- M^T * R.
// B-frag: K-half0 = bf16_hi(R), K-half1 = bf16_lo(R - hi) -> carry is ~fp32.
// D layout (measured m89/m91): d[j] = R'[4g+j][c]  == next B slots. No shuffles.
// ---------------------------------------------------------------------------
__global__ __launch_bounds__(256) void seg_mfma(const uint4* __restrict__ TA,
                                                const int* __restrict__ x,
                                                float* __restrict__ P) {
    const int wid  = blockIdx.x*4 + (threadIdx.x >> 6);
    const int lane = threadIdx.x & 63;
    const int s = wid & (SEGS-1), b = wid >> 3;
    const int g = lane >> 4, c = lane & 15;
    const int4* __restrict__ xp =
        reinterpret_cast<const int4*>(x + (size_t)b*LL + s*(STEPS*4));
    const f32x4 zero = {0.f, 0.f, 0.f, 0.f};
    f32x4 d = zero;
    unsigned h01 = ((4*g+0==c)?0x3F80u:0u) | (((4*g+1==c)?0x3F80u:0u) << 16);
    unsigned h23 = ((4*g+2==c)?0x3F80u:0u) | (((4*g+3==c)?0x3F80u:0u) << 16);
    unsigned l01 = 0u, l23 = 0u;

    #pragma unroll 4
    for (int t = 0; t < STEPS; ++t) {
        const int4 xv = xp[t];
        const int m = (xv.x<<3) | (xv.y<<2) | (xv.z<<1) | xv.w;
        const uint4 av = TA[(size_t)((s*STEPS + t)*16 + m)*64 + lane];
        union { uint4 u; s16x8 v; } ua, ub;
        ua.u = av;
        ub.u = make_uint4(h01, h23, l01, l23);
        d = __builtin_amdgcn_mfma_f32_16x16x32_bf16(ua.v, ub.v, zero, 0, 0, 0);
        asm("v_cvt_pk_bf16_f32 %0, %1, %2" : "=v"(h01) : "v"(d[0]), "v"(d[1]));
        asm("v_cvt_pk_bf16_f32 %0, %1, %2" : "=v"(h23) : "v"(d[2]), "v"(d[3]));
        const float r0 = d[0] - __uint_as_float(h01 << 16);
        const float r1 = d[1] - __uint_as_float(h01 & 0xFFFF0000u);
        const float r2 = d[2] - __uint_as_float(h23 << 16);
        const float r3 = d[3] - __uint_as_float(h23 & 0xFFFF0000u);
        asm("v_cvt_pk_bf16_f32 %0, %1, %2" : "=v"(l01) : "v"(r0), "v"(r1));
        asm("v_cvt_pk_bf16_f32 %0, %1, %2" : "=v"(l23) : "v"(r2), "v"(r3));
    }
    // store R = (segment product)^T, f32 row-major; d[j] = R[4g+j][c]
    float* Pp = P + (size_t)wid*256;
    #pragma unroll
    for (int j = 0; j < 4; ++j) Pp[(4*g+j)*16 + c] = d[j];
}

// ---------------------------------------------------------------------------
// Kernel C: per-batch tree combine of 8 transposed partials (fp32).
// trace(total) = trace(R7 R6 ... R0). Block = 4 batches x 64 threads.
// ---------------------------------------------------------------------------
__device__ inline void mul16(float* mats, int sx, int sy, int sd, int j) {
    const float* X = &mats[sx*SLOT + j*16];   // row j of X
    const float* Y = &mats[sy*SLOT];
    float4 o0 = make_float4(0.f,0.f,0.f,0.f), o1 = o0, o2 = o0, o3 = o0;
    #pragma unroll
    for (int i = 0; i < 16; ++i) {
        const float a = X[i];
        const float4 y0 = *reinterpret_cast<const float4*>(Y + i*16 + 0);
        const float4 y1 = *reinterpret_cast<const float4*>(Y + i*16 + 4);
        const float4 y2 = *reinterpret_cast<const float4*>(Y + i*16 + 8);
        const float4 y3 = *reinterpret_cast<const float4*>(Y + i*16 + 12);
        FMA4(o0, a, y0); FMA4(o1, a, y1); FMA4(o2, a, y2); FMA4(o3, a, y3);
    }
    float* Dq = &mats[sd*SLOT + j*16];
    *reinterpret_cast<float4*>(Dq + 0)  = o0;
    *reinterpret_cast<float4*>(Dq + 4)  = o1;
    *reinterpret_cast<float4*>(Dq + 8)  = o2;
    *reinterpret_cast<float4*>(Dq + 12) = o3;
}

__global__ __launch_bounds__(256) void combine8(const float* __restrict__ P,
                                                float* __restrict__ out) {
    __shared__ float mats[48 * SLOT];          // 4 batches x 12 slots
    const int t = threadIdx.x;
    const int b0 = blockIdx.x * 4;

    const float4* Pb = reinterpret_cast<const float4*>(P) + (size_t)b0 * 8 * 64;
    #pragma unroll
    for (int k = 0; k < 8; ++k) {
        const int gi = k*256 + t;              // 0..2047 float4s
        const float4 v = Pb[gi];
        const int gs = gi >> 6, w = gi & 63;   // global slot, word
        const int ls = (gs >> 3)*12 + (gs & 7);
        *reinterpret_cast<float4*>(&mats[ls*SLOT + w*4]) = v;
    }
    __syncthreads();

    const int p = t >> 4, j = t & 15;
    { const int q = p >> 2, i = p & 3;                 // L0: R_{2i+1} @ R_{2i}
      mul16(mats, q*12 + 2*i + 1, q*12 + 2*i, q*12 + 8 + i, j); }
    __syncthreads();
    if (p < 8) { const int q = p >> 1, i = p & 1;      // L1
      mul16(mats, q*12 + 8 + 2*i + 1, q*12 + 8 + 2*i, q*12 + i, j); }
    __syncthreads();
    if (p < 4) mul16(mats, p*12 + 1, p*12 + 0, p*12 + 2, j);   // L2
    __syncthreads();

    if (p < 4) {
        float dg = mats[(p*12 + 2)*SLOT + j*17];   // diag (j,j)
        #pragma unroll
        for (int off = 8; off >= 1; off >>= 1) dg += __shfl_xor(dg, off, 16);
        if (j == 0) out[b0 + p] = logf(dg);
    }
}

// ---------------------------------------------------------------------------
// Fallback (tiny ws): verified R1 raw-chain fp32 path.
// ---------------------------------------------------------------------------
__global__ void seg_prod1(const float* __restrict__ T, const int* __restrict__ x,
                          float* __restrict__ P, const int S, const int lgS) {
    const int tid  = blockIdx.x * blockDim.x + threadIdx.x;
    const int j    = tid & 15;
    const int item = tid >> 4;
    if (item >= BB * S) return;
    const int s = item & (S - 1);
    const int b = item >> lgS;
    float c[16];
    #pragma unroll
    for (int q = 0; q < 16; ++q) c[q] = (q == j) ? 1.f : 0.f;
    const int nsteps = LL / S;
    const int base   = s * nsteps;
    for (int cc = 0; cc < nsteps; ++cc) {
        const int l = base + cc;
        const int xv = x[(size_t)b*LL + l];
        const float4* Mrow = reinterpret_cast<const float4*>(T + ((size_t)l*2 + xv)*256);
        float4 n0 = make_float4(0.f,0.f,0.f,0.f), n1 = n0, n2 = n0, n3 = n0;
        #pragma unroll
        for (int i = 0; i < 16; ++i) {
            const float a = c[i];
            const float4 r0 = Mrow[i*4+0], r1 = Mrow[i*4+1], r2 = Mrow[i*4+2], r3 = Mrow[i*4+3];
            FMA4(n0, a, r0); FMA4(n1, a, r1); FMA4(n2, a, r2); FMA4(n3, a, r3);
        }
        c[0]=n0.x; c[1]=n0.y; c[2]=n0.z; c[3]=n0.w;
        c[4]=n1.x; c[5]=n1.y; c[6]=n1.z; c[7]=n1.w;
        c[8]=n2.x; c[9]=n2.y; c[10]=n2.z; c[11]=n2.w;
        c[12]=n3.x; c[13]=n3.y; c[14]=n3.z; c[15]=n3.w;
    }
    float4* Pp = reinterpret_cast<float4*>(P + (size_t)item*256 + j*16);
    Pp[0] = make_float4(c[0],c[1],c[2],c[3]);
    Pp[1] = make_float4(c[4],c[5],c[6],c[7]);
    Pp[2] = make_float4(c[8],c[9],c[10],c[11]);
    Pp[3] = make_float4(c[12],c[13],c[14],c[15]);
}

__global__ void combine_gen(const float* __restrict__ P, float* __restrict__ out,
                            const int S) {
    const int g = threadIdx.x >> 4;
    const int j = threadIdx.x & 15;
    const int b = blockIdx.x * 4 + g;
    float c[16];
    {
        const float4* p0 = reinterpret_cast<const float4*>(P + (size_t)(b*S)*256 + j*16);
        const float4 v0 = p0[0], v1 = p0[1], v2 = p0[2], v3 = p0[3];
        c[0]=v0.x; c[1]=v0.y; c[2]=v0.z; c[3]=v0.w;
        c[4]=v1.x; c[5]=v1.y; c[6]=v1.z; c[7]=v1.w;
        c[8]=v2.x; c[9]=v2.y; c[10]=v2.z; c[11]=v2.w;
        c[12]=v3.x; c[13]=v3.y; c[14]=v3.z; c[15]=v3.w;
    }
    for (int s = 1; s < S; ++s) {
        const float4* Mrow = reinterpret_cast<const float4*>(P + (size_t)(b*S + s)*256);
        float4 n0 = make_float4(0.f,0.f,0.f,0.f), n1 = n0, n2 = n0, n3 = n0;
        #pragma unroll
        for (int i = 0; i < 16; ++i) {
            const float a = c[i];
            const float4 r0 = Mrow[i*4+0], r1 = Mrow[i*4+1], r2 = Mrow[i*4+2], r3 = Mrow[i*4+3];
            FMA4(n0, a, r0); FMA4(n1, a, r1); FMA4(n2, a, r2); FMA4(n3, a, r3);
        }
        c[0]=n0.x; c[1]=n0.y; c[2]=n0.z; c[3]=n0.w;
        c[4]=n1.x; c[5]=n1.y; c[6]=n1.z; c[7]=n1.w;
        c[8]=n2.x; c[9]=n2.y; c[10]=n2.z; c[11]=n2.w;
        c[12]=n3.x; c[13]=n3.y; c[14]=n3.z; c[15]=n3.w;
    }
    float diag = 0.f;
    #pragma unroll
    for (int k = 0; k < 16; ++k) diag = (k == j) ? c[k] : diag;
    #pragma unroll
    for (int off = 8; off >= 1; off >>= 1) diag += __shfl_xor(diag, off, 16);
    if (j == 0) out[b] = logf(diag);
}

// ---------------------------------------------------------------------------
extern "C" void kernel_launch(void* const* d_in, const int* in_sizes, int n_in,
                              void* d_out, int out_size, void* d_ws, size_t ws_size,
                              hipStream_t stream) {
    const int*   x  = (const int*)d_in[0];    // (B, L) int32
    const float* km = (const float*)d_in[1];  // (L, PHYS, D, D) fp32
    float* out = (float*)d_out;               // (B,) fp32

    const size_t t4b = (size_t)NCHUNK4 * 16 * 256 * sizeof(float);   // 4 MiB
    const size_t tab = (size_t)NCHUNK4 * 16 * 64 * sizeof(uint4);    // 4 MiB
    const size_t pb  = (size_t)BB * SEGS * 256 * sizeof(float);      // 8 MiB

    if (ws_size >= t4b + tab + pb) {
        float* T4 = (float*)d_ws;
        uint4* TA = (uint4*)((char*)d_ws + t4b);
        float* P  = (float*)((char*)d_ws + t4b + tab);
        build_table<<<NCHUNK4*16, 256, 0, stream>>>(km, T4);
        repackA<<<NCHUNK4*16/4, 256, 0, stream>>>(T4, TA);
        seg_mfma<<<BB*SEGS/4, 256, 0, stream>>>(TA, x, P);
        combine8<<<BB/4, 256, 0, stream>>>(P, out);
    } else {
        int S = 16;
        while (S > 1 && (size_t)BB * S * 256 * sizeof(float) > ws_size) S >>= 1;
        int lgS = 0; for (int t = S; t > 1; t >>= 1) ++lgS;
        float* P = (float*)d_ws;
        const int blocks = (BB*S*16 + 255) / 256;
        seg_prod1<<<blocks, 256, 0, stream>>>(km, x, P, S, lgS);
        combine_gen<<<BB/4, 64, 0, stream>>>(P, out, S);
    }
}

// Round 6
// 34.584 us; speedup vs baseline: 30.3425x; 1.1779x over previous
//
#include <hip/hip_runtime.h>
#include <math.h>

#define LL 1024
#define BB 1024
#define NCHUNK4 256
#define SEGS 8
#define STEPS 32           // chunk4 steps per segment
#define SLOT 260

typedef float f32x4 __attribute__((ext_vector_type(4)));
typedef short s16x8 __attribute__((ext_vector_type(8)));

#define FMA4(acc, s, v) { (acc).x += (s)*(v).x; (acc).y += (s)*(v).y; \
                          (acc).z += (s)*(v).z; (acc).w += (s)*(v).w; }

__device__ inline unsigned f2bf(float f) {   // RNE f32->bf16 bits
    unsigned u = __float_as_uint(f);
    return (u + 0x7FFFu + ((u >> 16) & 1u)) >> 16;
}

// ---------------------------------------------------------------------------
// Kernel 1: build 4-step chunk product AND emit bf16 A-fragment of M^T.
// Block = (c,m), 256 threads; product math identical to verified build_table.
// Fragment (verified R5): lane l (g=l>>4, c=l&15), elems j=0..3 = M[4g+j][c],
// elems 4..7 duplicate (second K-half pairs with carry's lo part).
// ---------------------------------------------------------------------------
__global__ __launch_bounds__(256) void build_frag(const float* __restrict__ km,
                                                  uint4* __restrict__ TA) {
    const int c = blockIdx.x >> 4;
    const int m = blockIdx.x & 15;
    const int t = threadIdx.x;
    const int i = t >> 4, k = t & 15;
    __shared__ float M[4][256];
    __shared__ float buf[256];
    const int xs0 = (m >> 3) & 1, xs1 = (m >> 2) & 1, xs2 = (m >> 1) & 1, xs3 = m & 1;
    M[0][t] = km[((4*c + 0)*2 + xs0)*256 + t];
    M[1][t] = km[((4*c + 1)*2 + xs1)*256 + t];
    M[2][t] = km[((4*c + 2)*2 + xs2)*256 + t];
    M[3][t] = km[((4*c + 3)*2 + xs3)*256 + t];
    __syncthreads();
    float acc = 0.f;
    #pragma unroll
    for (int j = 0; j < 16; ++j) acc += M[0][i*16+j] * M[1][j*16+k];
    buf[t] = acc;
    __syncthreads();
    acc = 0.f;
    #pragma unroll
    for (int j = 0; j < 16; ++j) acc += buf[i*16+j] * M[2][j*16+k];
    __syncthreads();
    buf[t] = acc;
    __syncthreads();
    acc = 0.f;
    #pragma unroll
    for (int j = 0; j < 16; ++j) acc += buf[i*16+j] * M[3][j*16+k];
    __syncthreads();               // all reads of buf done
    buf[t] = acc;                  // final product, f32, row-major
    __syncthreads();
    if (t < 64) {
        const int g = t >> 4, cc = t & 15;
        const unsigned a0 = f2bf(buf[(4*g+0)*16 + cc]);
        const unsigned a1 = f2bf(buf[(4*g+1)*16 + cc]);
        const unsigned a2 = f2bf(buf[(4*g+2)*16 + cc]);
        const unsigned a3 = f2bf(buf[(4*g+3)*16 + cc]);
        const unsigned w01 = a0 | (a1 << 16);
        const unsigned w23 = a2 | (a3 << 16);
        TA[(size_t)blockIdx.x*64 + t] = make_uint4(w01, w23, w01, w23);
    }
}

// ---------------------------------------------------------------------------
// 16x16 fp32 matmul in LDS, 64 threads per product:
// sub = (q=sub>>4, j=sub&15): computes out[j][4q..4q+3].
// ---------------------------------------------------------------------------
__device__ inline void mul16w(float* mats, int sx, int sy, int sd, int sub) {
    const int q = sub >> 4, j = sub & 15;
    const float* X = &mats[sx*SLOT + j*16];
    const float* Y = &mats[sy*SLOT + q*4];
    float4 o = make_float4(0.f, 0.f, 0.f, 0.f);
    #pragma unroll
    for (int i = 0; i < 16; ++i) {
        const float a = X[i];
        const float4 y = *reinterpret_cast<const float4*>(Y + i*16);
        FMA4(o, a, y);
    }
    *reinterpret_cast<float4*>(&mats[sd*SLOT + j*16 + q*4]) = o;
}

// ---------------------------------------------------------------------------
// Kernel 2: fused segment chains + combine. Block = batch, 512 thr = 8 waves.
// Wave s: transposed chain R <- T^T * R over its 32 chunks (verified R5 loop:
// B-frag K-half0 = bf16_hi(carry), K-half1 = bf16_lo remainder; D layout
// d[j] = R'[4g+j][c] lands exactly on next B slots -> no shuffles).
// Then LDS tree: trace(S0..S7) = trace(R7 R6 ... R0), fp32.
// ---------------------------------------------------------------------------
__global__ __launch_bounds__(512) void mps_fused(const uint4* __restrict__ TA,
                                                 const int* __restrict__ x,
                                                 float* __restrict__ out) {
    __shared__ float mats[12 * SLOT];
    const int tt   = threadIdx.x;
    const int b    = blockIdx.x;
    const int s    = tt >> 6;          // wave = segment
    const int lane = tt & 63;
    const int g = lane >> 4, c = lane & 15;
    const int4* __restrict__ xp =
        reinterpret_cast<const int4*>(x + (size_t)b*LL + s*(STEPS*4));

    const f32x4 zero = {0.f, 0.f, 0.f, 0.f};
    f32x4 d = zero;
    unsigned h01 = ((4*g+0==c)?0x3F80u:0u) | (((4*g+1==c)?0x3F80u:0u) << 16);
    unsigned h23 = ((4*g+2==c)?0x3F80u:0u) | (((4*g+3==c)?0x3F80u:0u) << 16);
    unsigned l01 = 0u, l23 = 0u;

    #pragma unroll 4
    for (int t = 0; t < STEPS; ++t) {
        const int4 xv = xp[t];
        const int m = (xv.x<<3) | (xv.y<<2) | (xv.z<<1) | xv.w;
        const uint4 av = TA[(size_t)((s*STEPS + t)*16 + m)*64 + lane];
        union { uint4 u; s16x8 v; } ua, ub;
        ua.u = av;
        ub.u = make_uint4(h01, h23, l01, l23);
        d = __builtin_amdgcn_mfma_f32_16x16x32_bf16(ua.v, ub.v, zero, 0, 0, 0);
        asm("v_cvt_pk_bf16_f32 %0, %1, %2" : "=v"(h01) : "v"(d[0]), "v"(d[1]));
        asm("v_cvt_pk_bf16_f32 %0, %1, %2" : "=v"(h23) : "v"(d[2]), "v"(d[3]));
        const float r0 = d[0] - __uint_as_float(h01 << 16);
        const float r1 = d[1] - __uint_as_float(h01 & 0xFFFF0000u);
        const float r2 = d[2] - __uint_as_float(h23 << 16);
        const float r3 = d[3] - __uint_as_float(h23 & 0xFFFF0000u);
        asm("v_cvt_pk_bf16_f32 %0, %1, %2" : "=v"(l01) : "v"(r0), "v"(r1));
        asm("v_cvt_pk_bf16_f32 %0, %1, %2" : "=v"(l23) : "v"(r2), "v"(r3));
    }
    // R_s into LDS slot s: d[j] = R_s[4g+j][c]
    #pragma unroll
    for (int j = 0; j < 4; ++j) mats[s*SLOT + (4*g+j)*16 + c] = d[j];
    __syncthreads();

    const int prod = tt >> 6, sub = tt & 63;
    // L0: slot(8+p) = R_{2p+1} @ R_{2p},  p = 0..3 (waves 0..3)
    if (tt < 256) mul16w(mats, 2*prod+1, 2*prod, 8+prod, sub);
    __syncthreads();
    // L1: slot(p) = slot(8+2p+1) @ slot(8+2p),  p = 0..1
    if (tt < 128) mul16w(mats, 8+2*prod+1, 8+2*prod, prod, sub);
    __syncthreads();
    // L2: slot(2) = slot(1) @ slot(0)
    if (tt < 64) mul16w(mats, 1, 0, 2, sub);
    __syncthreads();

    if (tt < 16) {
        float dg = mats[2*SLOT + tt*17];     // diag (tt,tt)
        #pragma unroll
        for (int off = 8; off >= 1; off >>= 1) dg += __shfl_xor(dg, off, 16);
        if (tt == 0) out[b] = logf(dg);
    }
}

// ---------------------------------------------------------------------------
// Fallback (tiny ws): verified R1 raw-chain fp32 path.
// ---------------------------------------------------------------------------
__global__ void seg_prod1(const float* __restrict__ T, const int* __restrict__ x,
                          float* __restrict__ P, const int S, const int lgS) {
    const int tid  = blockIdx.x * blockDim.x + threadIdx.x;
    const int j    = tid & 15;
    const int item = tid >> 4;
    if (item >= BB * S) return;
    const int s = item & (S - 1);
    const int b = item >> lgS;
    float c[16];
    #pragma unroll
    for (int q = 0; q < 16; ++q) c[q] = (q == j) ? 1.f : 0.f;
    const int nsteps = LL / S;
    const int base   = s * nsteps;
    for (int cc = 0; cc < nsteps; ++cc) {
        const int l = base + cc;
        const int xv = x[(size_t)b*LL + l];
        const float4* Mrow = reinterpret_cast<const float4*>(T + ((size_t)l*2 + xv)*256);
        float4 n0 = make_float4(0.f,0.f,0.f,0.f), n1 = n0, n2 = n0, n3 = n0;
        #pragma unroll
        for (int i = 0; i < 16; ++i) {
            const float a = c[i];
            const float4 r0 = Mrow[i*4+0], r1 = Mrow[i*4+1], r2 = Mrow[i*4+2], r3 = Mrow[i*4+3];
            FMA4(n0, a, r0); FMA4(n1, a, r1); FMA4(n2, a, r2); FMA4(n3, a, r3);
        }
        c[0]=n0.x; c[1]=n0.y; c[2]=n0.z; c[3]=n0.w;
        c[4]=n1.x; c[5]=n1.y; c[6]=n1.z; c[7]=n1.w;
        c[8]=n2.x; c[9]=n2.y; c[10]=n2.z; c[11]=n2.w;
        c[12]=n3.x; c[13]=n3.y; c[14]=n3.z; c[15]=n3.w;
    }
    float4* Pp = reinterpret_cast<float4*>(P + (size_t)item*256 + j*16);
    Pp[0] = make_float4(c[0],c[1],c[2],c[3]);
    Pp[1] = make_float4(c[4],c[5],c[6],c[7]);
    Pp[2] = make_float4(c[8],c[9],c[10],c[11]);
    Pp[3] = make_float4(c[12],c[13],c[14],c[15]);
}

__global__ void combine_gen(const float* __restrict__ P, float* __restrict__ out,
                            const int S) {
    const int g = threadIdx.x >> 4;
    const int j = threadIdx.x & 15;
    const int b = blockIdx.x * 4 + g;
    float c[16];
    {
        const float4* p0 = reinterpret_cast<const float4*>(P + (size_t)(b*S)*256 + j*16);
        const float4 v0 = p0[0], v1 = p0[1], v2 = p0[2], v3 = p0[3];
        c[0]=v0.x; c[1]=v0.y; c[2]=v0.z; c[3]=v0.w;
        c[4]=v1.x; c[5]=v1.y; c[6]=v1.z; c[7]=v1.w;
        c[8]=v2.x; c[9]=v2.y; c[10]=v2.z; c[11]=v2.w;
        c[12]=v3.x; c[13]=v3.y; c[14]=v3.z; c[15]=v3.w;
    }
    for (int s = 1; s < S; ++s) {
        const float4* Mrow = reinterpret_cast<const float4*>(P + (size_t)(b*S + s)*256);
        float4 n0 = make_float4(0.f,0.f,0.f,0.f), n1 = n0, n2 = n0, n3 = n0;
        #pragma unroll
        for (int i = 0; i < 16; ++i) {
            const float a = c[i];
            const float4 r0 = Mrow[i*4+0], r1 = Mrow[i*4+1], r2 = Mrow[i*4+2], r3 = Mrow[i*4+3];
            FMA4(n0, a, r0); FMA4(n1, a, r1); FMA4(n2, a, r2); FMA4(n3, a, r3);
        }
        c[0]=n0.x; c[1]=n0.y; c[2]=n0.z; c[3]=n0.w;
        c[4]=n1.x; c[5]=n1.y; c[6]=n1.z; c[7]=n1.w;
        c[8]=n2.x; c[9]=n2.y; c[10]=n2.z; c[11]=n2.w;
        c[12]=n3.x; c[13]=n3.y; c[14]=n3.z; c[15]=n3.w;
    }
    float diag = 0.f;
    #pragma unroll
    for (int k = 0; k < 16; ++k) diag = (k == j) ? c[k] : diag;
    #pragma unroll
    for (int off = 8; off >= 1; off >>= 1) diag += __shfl_xor(diag, off, 16);
    if (j == 0) out[b] = logf(diag);
}

// ---------------------------------------------------------------------------
extern "C" void kernel_launch(void* const* d_in, const int* in_sizes, int n_in,
                              void* d_out, int out_size, void* d_ws, size_t ws_size,
                              hipStream_t stream) {
    const int*   x  = (const int*)d_in[0];    // (B, L) int32
    const float* km = (const float*)d_in[1];  // (L, PHYS, D, D) fp32
    float* out = (float*)d_out;               // (B,) fp32

    const size_t tab = (size_t)NCHUNK4 * 16 * 64 * sizeof(uint4);    // 4 MiB

    if (ws_size >= tab) {
        uint4* TA = (uint4*)d_ws;
        build_frag<<<NCHUNK4*16, 256, 0, stream>>>(km, TA);
        mps_fused<<<BB, 512, 0, stream>>>(TA, x, out);
    } else {
        int S = 16;
        while (S > 1 && (size_t)BB * S * 256 * sizeof(float) > ws_size) S >>= 1;
        int lgS = 0; for (int t = S; t > 1; t >>= 1) ++lgS;
        float* P = (float*)d_ws;
        const int blocks = (BB*S*16 + 255) / 256;
        seg_prod1<<<blocks, 256, 0, stream>>>(km, x, P, S, lgS);
        combine_gen<<<BB/4, 64, 0, stream>>>(P, out, S);
    }
}

// Round 7
// 31.429 us; speedup vs baseline: 33.3881x; 1.1004x over previous
//
#include <hip/hip_runtime.h>
#include <math.h>

#define LL 1024
#define BB 1024
#define NCHUNK4 256
#define SEGS 8
#define STEPS 32           // chunk4 steps per segment
#define SLOT 260

typedef float f32x4 __attribute__((ext_vector_type(4)));
typedef short s16x8 __attribute__((ext_vector_type(8)));

#define FMA4(acc, s, v) { (acc).x += (s)*(v).x; (acc).y += (s)*(v).y; \
                          (acc).z += (s)*(v).z; (acc).w += (s)*(v).w; }

__device__ inline unsigned f2bf(float f) {   // RNE f32->bf16 bits
    unsigned u = __float_as_uint(f);
    return (u + 0x7FFFu + ((u >> 16) & 1u)) >> 16;
}

// ---------------------------------------------------------------------------
// Kernel 1: build 4-step chunk product AND emit deduped bf16 A-fragment of
// M^T. Block = (c,m), 256 threads; product math identical to verified
// build_table. Fragment (verified R5/R6): lane l (g=l>>4, c=l&15) holds
// elems j=0..3 = M[4g+j][c] packed in uint2; the second K-half (identical)
// is reconstructed in-register by the consumer.
// ---------------------------------------------------------------------------
__global__ __launch_bounds__(256) void build_frag(const float* __restrict__ km,
                                                  uint2* __restrict__ TA) {
    const int c = blockIdx.x >> 4;
    const int m = blockIdx.x & 15;
    const int t = threadIdx.x;
    const int i = t >> 4, k = t & 15;
    __shared__ float M[4][256];
    __shared__ float buf[256];
    const int xs0 = (m >> 3) & 1, xs1 = (m >> 2) & 1, xs2 = (m >> 1) & 1, xs3 = m & 1;
    M[0][t] = km[((4*c + 0)*2 + xs0)*256 + t];
    M[1][t] = km[((4*c + 1)*2 + xs1)*256 + t];
    M[2][t] = km[((4*c + 2)*2 + xs2)*256 + t];
    M[3][t] = km[((4*c + 3)*2 + xs3)*256 + t];
    __syncthreads();
    float acc = 0.f;
    #pragma unroll
    for (int j = 0; j < 16; ++j) acc += M[0][i*16+j] * M[1][j*16+k];
    buf[t] = acc;
    __syncthreads();
    acc = 0.f;
    #pragma unroll
    for (int j = 0; j < 16; ++j) acc += buf[i*16+j] * M[2][j*16+k];
    __syncthreads();
    buf[t] = acc;
    __syncthreads();
    acc = 0.f;
    #pragma unroll
    for (int j = 0; j < 16; ++j) acc += buf[i*16+j] * M[3][j*16+k];
    __syncthreads();               // all reads of buf done
    buf[t] = acc;                  // final product, f32, row-major
    __syncthreads();
    if (t < 64) {
        const int g = t >> 4, cc = t & 15;
        const unsigned a0 = f2bf(buf[(4*g+0)*16 + cc]);
        const unsigned a1 = f2bf(buf[(4*g+1)*16 + cc]);
        const unsigned a2 = f2bf(buf[(4*g+2)*16 + cc]);
        const unsigned a3 = f2bf(buf[(4*g+3)*16 + cc]);
        TA[(size_t)blockIdx.x*64 + t] = make_uint2(a0 | (a1 << 16), a2 | (a3 << 16));
    }
}

// ---------------------------------------------------------------------------
// 16x16 fp32 matmul in LDS, 64 threads per product:
// sub = (q=sub>>4, j=sub&15): computes out[j][4q..4q+3].
// ---------------------------------------------------------------------------
__device__ inline void mul16w(float* mats, int sx, int sy, int sd, int sub) {
    const int q = sub >> 4, j = sub & 15;
    const float* X = &mats[sx*SLOT + j*16];
    const float* Y = &mats[sy*SLOT + q*4];
    float4 o = make_float4(0.f, 0.f, 0.f, 0.f);
    #pragma unroll
    for (int i = 0; i < 16; ++i) {
        const float a = X[i];
        const float4 y = *reinterpret_cast<const float4*>(Y + i*16);
        FMA4(o, a, y);
    }
    *reinterpret_cast<float4*>(&mats[sd*SLOT + j*16 + q*4]) = o;
}

// ---------------------------------------------------------------------------
// Kernel 2: fused segment chains + combine. Block = batch, 512 thr = 8 waves.
// Wave s: transposed chain R <- T^T * R over its 32 chunks (verified R5/R6
// loop: B-frag K-half0 = bf16_hi(carry), K-half1 = bf16_lo remainder; D
// layout d[j] = R'[4g+j][c] lands exactly on next B slots -> no shuffles).
// Then LDS tree: trace(S0..S7) = trace(R7 R6 ... R0), fp32.
// ---------------------------------------------------------------------------
__global__ __launch_bounds__(512) void mps_fused(const uint2* __restrict__ TA,
                                                 const int* __restrict__ x,
                                                 float* __restrict__ out) {
    __shared__ float mats[12 * SLOT];
    const int tt   = threadIdx.x;
    const int b    = blockIdx.x;
    const int s    = tt >> 6;          // wave = segment
    const int lane = tt & 63;
    const int g = lane >> 4, c = lane & 15;
    const int4* __restrict__ xp =
        reinterpret_cast<const int4*>(x + (size_t)b*LL + s*(STEPS*4));

    const f32x4 zero = {0.f, 0.f, 0.f, 0.f};
    f32x4 d = zero;
    unsigned h01 = ((4*g+0==c)?0x3F80u:0u) | (((4*g+1==c)?0x3F80u:0u) << 16);
    unsigned h23 = ((4*g+2==c)?0x3F80u:0u) | (((4*g+3==c)?0x3F80u:0u) << 16);
    unsigned l01 = 0u, l23 = 0u;

    #pragma unroll 8
    for (int t = 0; t < STEPS; ++t) {
        const int4 xv = xp[t];
        const int m = (xv.x<<3) | (xv.y<<2) | (xv.z<<1) | xv.w;
        const uint2 av = TA[(size_t)((s*STEPS + t)*16 + m)*64 + lane];
        union { uint4 u; s16x8 v; } ua, ub;
        ua.u = make_uint4(av.x, av.y, av.x, av.y);   // duplicated K-half
        ub.u = make_uint4(h01, h23, l01, l23);
        d = __builtin_amdgcn_mfma_f32_16x16x32_bf16(ua.v, ub.v, zero, 0, 0, 0);
        asm("v_cvt_pk_bf16_f32 %0, %1, %2" : "=v"(h01) : "v"(d[0]), "v"(d[1]));
        asm("v_cvt_pk_bf16_f32 %0, %1, %2" : "=v"(h23) : "v"(d[2]), "v"(d[3]));
        const float r0 = d[0] - __uint_as_float(h01 << 16);
        const float r1 = d[1] - __uint_as_float(h01 & 0xFFFF0000u);
        const float r2 = d[2] - __uint_as_float(h23 << 16);
        const float r3 = d[3] - __uint_as_float(h23 & 0xFFFF0000u);
        asm("v_cvt_pk_bf16_f32 %0, %1, %2" : "=v"(l01) : "v"(r0), "v"(r1));
        asm("v_cvt_pk_bf16_f32 %0, %1, %2" : "=v"(l23) : "v"(r2), "v"(r3));
    }
    // R_s into LDS slot s: d[j] = R_s[4g+j][c]
    #pragma unroll
    for (int j = 0; j < 4; ++j) mats[s*SLOT + (4*g+j)*16 + c] = d[j];
    __syncthreads();

    const int prod = tt >> 6, sub = tt & 63;
    // L0: slot(8+p) = R_{2p+1} @ R_{2p},  p = 0..3 (waves 0..3)
    if (tt < 256) mul16w(mats, 2*prod+1, 2*prod, 8+prod, sub);
    __syncthreads();
    // L1: slot(p) = slot(8+2p+1) @ slot(8+2p),  p = 0..1
    if (tt < 128) mul16w(mats, 8+2*prod+1, 8+2*prod, prod, sub);
    __syncthreads();
    // L2: slot(2) = slot(1) @ slot(0)
    if (tt < 64) mul16w(mats, 1, 0, 2, sub);
    __syncthreads();

    if (tt < 16) {
        float dg = mats[2*SLOT + tt*17];     // diag (tt,tt)
        #pragma unroll
        for (int off = 8; off >= 1; off >>= 1) dg += __shfl_xor(dg, off, 16);
        if (tt == 0) out[b] = logf(dg);
    }
}

// ---------------------------------------------------------------------------
// Fallback (tiny ws): verified R1 raw-chain fp32 path.
// ---------------------------------------------------------------------------
__global__ void seg_prod1(const float* __restrict__ T, const int* __restrict__ x,
                          float* __restrict__ P, const int S, const int lgS) {
    const int tid  = blockIdx.x * blockDim.x + threadIdx.x;
    const int j    = tid & 15;
    const int item = tid >> 4;
    if (item >= BB * S) return;
    const int s = item & (S - 1);
    const int b = item >> lgS;
    float c[16];
    #pragma unroll
    for (int q = 0; q < 16; ++q) c[q] = (q == j) ? 1.f : 0.f;
    const int nsteps = LL / S;
    const int base   = s * nsteps;
    for (int cc = 0; cc < nsteps; ++cc) {
        const int l = base + cc;
        const int xv = x[(size_t)b*LL + l];
        const float4* Mrow = reinterpret_cast<const float4*>(T + ((size_t)l*2 + xv)*256);
        float4 n0 = make_float4(0.f,0.f,0.f,0.f), n1 = n0, n2 = n0, n3 = n0;
        #pragma unroll
        for (int i = 0; i < 16; ++i) {
            const float a = c[i];
            const float4 r0 = Mrow[i*4+0], r1 = Mrow[i*4+1], r2 = Mrow[i*4+2], r3 = Mrow[i*4+3];
            FMA4(n0, a, r0); FMA4(n1, a, r1); FMA4(n2, a, r2); FMA4(n3, a, r3);
        }
        c[0]=n0.x; c[1]=n0.y; c[2]=n0.z; c[3]=n0.w;
        c[4]=n1.x; c[5]=n1.y; c[6]=n1.z; c[7]=n1.w;
        c[8]=n2.x; c[9]=n2.y; c[10]=n2.z; c[11]=n2.w;
        c[12]=n3.x; c[13]=n3.y; c[14]=n3.z; c[15]=n3.w;
    }
    float4* Pp = reinterpret_cast<float4*>(P + (size_t)item*256 + j*16);
    Pp[0] = make_float4(c[0],c[1],c[2],c[3]);
    Pp[1] = make_float4(c[4],c[5],c[6],c[7]);
    Pp[2] = make_float4(c[8],c[9],c[10],c[11]);
    Pp[3] = make_float4(c[12],c[13],c[14],c[15]);
}

__global__ void combine_gen(const float* __restrict__ P, float* __restrict__ out,
                            const int S) {
    const int g = threadIdx.x >> 4;
    const int j = threadIdx.x & 15;
    const int b = blockIdx.x * 4 + g;
    float c[16];
    {
        const float4* p0 = reinterpret_cast<const float4*>(P + (size_t)(b*S)*256 + j*16);
        const float4 v0 = p0[0], v1 = p0[1], v2 = p0[2], v3 = p0[3];
        c[0]=v0.x; c[1]=v0.y; c[2]=v0.z; c[3]=v0.w;
        c[4]=v1.x; c[5]=v1.y; c[6]=v1.z; c[7]=v1.w;
        c[8]=v2.x; c[9]=v2.y; c[10]=v2.z; c[11]=v2.w;
        c[12]=v3.x; c[13]=v3.y; c[14]=v3.z; c[15]=v3.w;
    }
    for (int s = 1; s < S; ++s) {
        const float4* Mrow = reinterpret_cast<const float4*>(P + (size_t)(b*S + s)*256);
        float4 n0 = make_float4(0.f,0.f,0.f,0.f), n1 = n0, n2 = n0, n3 = n0;
        #pragma unroll
        for (int i = 0; i < 16; ++i) {
            const float a = c[i];
            const float4 r0 = Mrow[i*4+0], r1 = Mrow[i*4+1], r2 = Mrow[i*4+2], r3 = Mrow[i*4+3];
            FMA4(n0, a, r0); FMA4(n1, a, r1); FMA4(n2, a, r2); FMA4(n3, a, r3);
        }
        c[0]=n0.x; c[1]=n0.y; c[2]=n0.z; c[3]=n0.w;
        c[4]=n1.x; c[5]=n1.y; c[6]=n1.z; c[7]=n1.w;
        c[8]=n2.x; c[9]=n2.y; c[10]=n2.z; c[11]=n2.w;
        c[12]=n3.x; c[13]=n3.y; c[14]=n3.z; c[15]=n3.w;
    }
    float diag = 0.f;
    #pragma unroll
    for (int k = 0; k < 16; ++k) diag = (k == j) ? c[k] : diag;
    #pragma unroll
    for (int off = 8; off >= 1; off >>= 1) diag += __shfl_xor(diag, off, 16);
    if (j == 0) out[b] = logf(diag);
}

// ---------------------------------------------------------------------------
extern "C" void kernel_launch(void* const* d_in, const int* in_sizes, int n_in,
                              void* d_out, int out_size, void* d_ws, size_t ws_size,
                              hipStream_t stream) {
    const int*   x  = (const int*)d_in[0];    // (B, L) int32
    const float* km = (const float*)d_in[1];  // (L, PHYS, D, D) fp32
    float* out = (float*)d_out;               // (B,) fp32

    const size_t tab = (size_t)NCHUNK4 * 16 * 64 * sizeof(uint2);    // 2 MiB

    if (ws_size >= tab) {
        uint2* TA = (uint2*)d_ws;
        build_frag<<<NCHUNK4*16, 256, 0, stream>>>(km, TA);
        mps_fused<<<BB, 512, 0, stream>>>(TA, x, out);
    } else {
        int S = 16;
        while (S > 1 && (size_t)BB * S * 256 * sizeof(float) > ws_size) S >>= 1;
        int lgS = 0; for (int t = S; t > 1; t >>= 1) ++lgS;
        float* P = (float*)d_ws;
        const int blocks = (BB*S*16 + 255) / 256;
        seg_prod1<<<blocks, 256, 0, stream>>>(km, x, P, S, lgS);
        combine_gen<<<BB/4, 64, 0, stream>>>(P, out, S);
    }
}